// Round 8
// baseline (4887.181 us; speedup 1.0000x reference)
//
#include <hip/hip_runtime.h>
#include <cmath>

#define HID 150
#define FOURH 600
#define BATCH 64
#define TLEN 2048
#define NKS 5  // 32-wide k-slices over k padded 150->160

typedef __attribute__((ext_vector_type(2))) _Float16 half2_t;

#if defined(__has_builtin)
#if __has_builtin(__builtin_amdgcn_fdot2)
#define FDOT2(a, b, c) __builtin_amdgcn_fdot2((a), (b), (c), false)
#endif
#endif
#ifndef FDOT2
__device__ __forceinline__ float fdot2_fb(half2_t a, half2_t b, float c) {
    return c + (float)a.x * (float)b.x + (float)a.y * (float)b.y;
}
#define FDOT2(a, b, c) fdot2_fb((a), (b), (c))
#endif

__device__ __forceinline__ float sigmoidf_(float x) {
    return 1.0f / (1.0f + __expf(-x));
}
__device__ __forceinline__ float tanhf_(float x) {
    return 1.0f - 2.0f / (__expf(2.0f * x) + 1.0f);
}

#define H2(x) __builtin_bit_cast(half2_t, (x))

// Streaming-coalesced packed weights. float4 slot f (0..15) of thread
// t = ks*150+j lives at half2 index (f*750 + t)*4 + e. Slot f covers gate
// g = f&3, quarter Q = f>>2; element e is the k-pair k0 = ks*32 + Q*8 + 2e.
// A wave's load of slot f is lane-contiguous (1 KB/instruction).
__global__ void pack_wh2(const float* __restrict__ Wh0, const float* __restrict__ Wh1,
                         half2_t* __restrict__ dst) {
    int idx = blockIdx.x * 256 + threadIdx.x;
    if (idx >= 96000) return;
    int layer = idx / 48000, r = idx - layer * 48000;
    int e = r & 3, f4 = r >> 2;
    int f = f4 / 750, t = f4 - f * 750;
    int ks = t / HID, j = t - ks * HID;
    int Q = f >> 2, g = f & 3;
    int k0 = ks * 32 + Q * 8 + 2 * e;
    const float* Wh = layer ? Wh1 : Wh0;
    float a  = (k0 < HID)     ? Wh[(size_t)k0 * FOURH + g * HID + j]       : 0.f;
    float bb = (k0 + 1 < HID) ? Wh[(size_t)(k0 + 1) * FOURH + g * HID + j] : 0.f;
    half2_t h; h.x = (_Float16)a; h.y = (_Float16)bb;
    dst[idx] = h;
}

// One quarter of the k-slice: 4 coalesced float4 weight loads (one per gate),
// one 16B LDS h read, 16 fdot2.
#define DOTQ(Q) { \
  float4 wf0 = Wtt[((Q)*4+0)*750]; \
  float4 wf1 = Wtt[((Q)*4+1)*750]; \
  float4 wf2 = Wtt[((Q)*4+2)*750]; \
  float4 wf3 = Wtt[((Q)*4+3)*750]; \
  float4 hu = *(const float4*)(const void*)&h16[ks * 32 + (Q) * 8]; \
  half2_t u0 = H2(hu.x), u1 = H2(hu.y), u2 = H2(hu.z), u3 = H2(hu.w); \
  a0 = FDOT2(u0, H2(wf0.x), a0); a0 = FDOT2(u1, H2(wf0.y), a0); \
  a0 = FDOT2(u2, H2(wf0.z), a0); a0 = FDOT2(u3, H2(wf0.w), a0); \
  a1 = FDOT2(u0, H2(wf1.x), a1); a1 = FDOT2(u1, H2(wf1.y), a1); \
  a1 = FDOT2(u2, H2(wf1.z), a1); a1 = FDOT2(u3, H2(wf1.w), a1); \
  a2 = FDOT2(u0, H2(wf2.x), a2); a2 = FDOT2(u1, H2(wf2.y), a2); \
  a2 = FDOT2(u2, H2(wf2.z), a2); a2 = FDOT2(u3, H2(wf2.w), a2); \
  a3 = FDOT2(u0, H2(wf3.x), a3); a3 = FDOT2(u1, H2(wf3.y), a3); \
  a3 = FDOT2(u2, H2(wf3.z), a3); a3 = FDOT2(u3, H2(wf3.w), a3); }

// Fused slot kernel. Grid layout (in order, so recur WGs launch first):
//   [ nA*64 recur part-A | nB*64 recur part-B | nX0*64*(C/16) xproj-0 | nX1*... xproj-1 ]
// Recur: one WG per batch element, G=1, thread (j,ks) streams its 64 packed
// half2 weights from L2 each step (coalesced). xproj: 16 rows of one batch
// per WG, runs on the CUs the recurrence leaves idle.
__global__ __launch_bounds__(768)
__attribute__((amdgpu_waves_per_eu(3, 3)))
void fused_slot(
    int nA, const float* __restrict__ xpA, const half2_t* __restrict__ whpA,
    float* __restrict__ stA, int t0A,
    int nB, const float* __restrict__ xpB, const half2_t* __restrict__ whpB,
    float* __restrict__ stB, int t0B,
    int nX0, const float* __restrict__ X0, const float* __restrict__ Wx0,
    const float* __restrict__ bias0, float* __restrict__ xd0, int tX0,
    int nX1, const float* __restrict__ X1, const float* __restrict__ Wx1,
    const float* __restrict__ bias1, float* __restrict__ xd1, int tX1,
    float* __restrict__ out, int C)
{
    __shared__ __align__(16) char lds_u[12800];
    const int w = blockIdx.x;
    const int nrec = (nA + nB) * 64;
    const int tid = threadIdx.x;

    if (w < nrec) {
        // ================= recurrence =================
        _Float16* h16 = (_Float16*)lds_u;                          // [160]
        float (*part_s)[4][152] = (float (*)[4][152])(lds_u + 512); // [5][4][152]
        const int isB = (w >= nA * 64);
        const int b = w & 63;
        const float*   xp    = isB ? xpB  : xpA;
        const float4*  Wt    = (const float4*)(isB ? whpB : whpA);
        float*         state = isB ? stB  : stA;
        const int      t0    = isB ? t0B  : t0A;

        const int tidc = (tid < 750) ? tid : 749;
        const int ks = tidc / HID;
        const int j  = tidc - ks * HID;
        const float4* Wtt = Wt + tidc;

        float cst = 0.f;
        if (tid < 160) {
            float hv = 0.f;
            if (t0 != 0 && tid < HID) {
                cst = state[b * 300 + tid];
                hv  = state[b * 300 + HID + tid];
            }
            h16[tid] = (_Float16)hv;
        }
        __syncthreads();

        const float* xpb = xp + (size_t)b * C * FOURH;
        float* outb = out + ((size_t)b * TLEN + t0) * HID;

        float xn0 = 0.f, xn1 = 0.f, xn2 = 0.f, xn3 = 0.f;
        if (tid < HID) {
            xn0 = xpb[tid];
            xn1 = xpb[HID + tid];
            xn2 = xpb[2 * HID + tid];
            xn3 = xpb[3 * HID + tid];
        }

        for (int i = 0; i < C; ++i) {
            // ---- Stage A: 16 coalesced weight loads + 64 fdot2 (750 thr) ----
            if (tid < 750) {
                float a0 = 0.f, a1 = 0.f, a2 = 0.f, a3 = 0.f;
                DOTQ(0) DOTQ(1) DOTQ(2) DOTQ(3)
                part_s[ks][0][j] = a0;
                part_s[ks][1][j] = a1;
                part_s[ks][2][j] = a2;
                part_s[ks][3][j] = a3;
            }
            __syncthreads();

            // ---- Stage B: reduce, activate, update c/h (150 thr) ----
            if (tid < HID) {
                float p0 = xn0, p1 = xn1, p2 = xn2, p3 = xn3;
                if (i + 1 < C) {
                    const float* p = &xpb[(size_t)(i + 1) * FOURH];
                    xn0 = p[tid];
                    xn1 = p[HID + tid];
                    xn2 = p[2 * HID + tid];
                    xn3 = p[3 * HID + tid];
                }
                float z0 = p0, z1 = p1, z2 = p2, z3 = p3;
                #pragma unroll
                for (int s = 0; s < NKS; ++s) {
                    z0 += part_s[s][0][tid];
                    z1 += part_s[s][1][tid];
                    z2 += part_s[s][2][tid];
                    z3 += part_s[s][3][tid];
                }
                float ig = sigmoidf_(z0);
                float fg = sigmoidf_(z1);
                float gg = tanhf_(z2);
                float og = sigmoidf_(z3);
                cst = fg * cst + ig * gg;
                float hn = og * tanhf_(cst);
                h16[tid] = (_Float16)hn;
                outb[(size_t)i * HID + tid] = hn;
            }
            __syncthreads();
        }

        if (tid < HID) {
            state[b * 300 + tid] = cst;
            state[b * 300 + HID + tid] = (float)h16[tid];
        }
    } else {
        // ================= xproj GEMM (16 rows per WG) =================
        float* xt = (float*)lds_u;  // [150][20] padded
        int x = w - nrec;
        const int xg = C / 16;
        const float *X, *Wx, *bias; float* xd; int t0x;
        if (x < nX0 * 64 * xg) {
            X = X0; Wx = Wx0; bias = bias0; xd = xd0; t0x = tX0;
        } else {
            x -= nX0 * 64 * xg;
            X = X1; Wx = Wx1; bias = bias1; xd = xd1; t0x = tX1;
        }
        const int b  = x / xg;
        const int i0 = (x - b * xg) * 16;
        const float* Xbase = X + ((size_t)(b * TLEN + t0x + i0)) * HID;

        for (int i2 = tid; i2 < 16 * HID; i2 += 768) {
            int r = i2 / HID, k = i2 - r * HID;
            xt[k * 20 + r] = Xbase[(size_t)r * HID + k];
        }
        __syncthreads();

        if (tid < FOURH) {
            float acc[16];
            #pragma unroll
            for (int r = 0; r < 16; ++r) acc[r] = 0.f;
            for (int k = 0; k < HID; ++k) {
                float wv = Wx[(size_t)k * FOURH + tid];
                #pragma unroll
                for (int r4 = 0; r4 < 4; ++r4) {
                    float4 xv = *(const float4*)&xt[k * 20 + r4 * 4];
                    acc[r4*4+0] += xv.x * wv;
                    acc[r4*4+1] += xv.y * wv;
                    acc[r4*4+2] += xv.z * wv;
                    acc[r4*4+3] += xv.w * wv;
                }
            }
            float bv = bias[tid];
            float* o = xd + ((size_t)b * C + i0) * FOURH + tid;
            #pragma unroll
            for (int r = 0; r < 16; ++r) o[(size_t)r * FOURH] = acc[r] + bv;
        }
    }
}

extern "C" void kernel_launch(void* const* d_in, const int* in_sizes, int n_in,
                              void* d_out, int out_size, void* d_ws, size_t ws_size,
                              hipStream_t stream) {
    const float* xs  = (const float*)d_in[0];
    const float* Wx0 = (const float*)d_in[1];
    const float* Wh0 = (const float*)d_in[2];
    const float* b0  = (const float*)d_in[3];
    const float* Wx1 = (const float*)d_in[4];
    const float* Wh1 = (const float*)d_in[5];
    const float* b1  = (const float*)d_in[6];
    float* out = (float*)d_out;

    // 4 chunk buffers (xp0[2], xp1[2]) + packed weights + states.
    int C = 256;
    {
        size_t need = 4ull * BATCH * C * FOURH * 4 + 96000ull * 4
                    + 2ull * BATCH * 300 * 4;
        if (need > ws_size) C = 128;
    }
    const size_t xpsz = (size_t)BATCH * C * FOURH * 4;
    char* p = (char*)d_ws;
    float* xp0[2]; float* xp1[2];
    xp0[0] = (float*)p; p += xpsz;
    xp0[1] = (float*)p; p += xpsz;
    xp1[0] = (float*)p; p += xpsz;
    xp1[1] = (float*)p; p += xpsz;
    half2_t* whp = (half2_t*)p; p += 96000ull * 4;
    float* st0 = (float*)p; p += (size_t)BATCH * 300 * 4;
    float* st1 = (float*)p;
    const half2_t* whp0 = whp;
    const half2_t* whp1 = whp + 48000;

    pack_wh2<<<dim3((96000 + 255) / 256), dim3(256), 0, stream>>>(Wh0, Wh1, whp);

    const int nchunk = TLEN / C;
    const int xg = C / 16;

    // Prologue: xproj(L0, chunk 0) -> xp0[0].
    fused_slot<<<dim3(64 * xg), dim3(768), 0, stream>>>(
        0, xp0[0], whp0, st0, 0,
        0, xp1[0], whp1, st1, 0,
        1, xs, Wx0, b0, xp0[0], 0,
        0, xs, Wx1, b1, xp1[0], 0,
        out, C);

    // Slot s: recur(L0 chunk s || L1 chunk s-2) || xproj(L0,s+1) || xproj(L1,s-1).
    // Every producer/consumer pair sits in different dispatches; xp buffers
    // are double-buffered by slot parity ((s-2)&1 == s&1).
    for (int s = 0; s <= nchunk + 1; ++s) {
        const int hasA  = (s < nchunk) ? 1 : 0;
        const int hasB  = (s >= 2) ? 1 : 0;
        const int hasX0 = (s + 1 < nchunk) ? 1 : 0;
        const int hasX1 = (s >= 1 && s - 1 < nchunk) ? 1 : 0;
        const int grid = (hasA + hasB) * 64 + (hasX0 + hasX1) * 64 * xg;
        fused_slot<<<dim3(grid), dim3(768), 0, stream>>>(
            hasA, xp0[s & 1], whp0, st0, s * C,
            hasB, xp1[s & 1], whp1, st1, (s - 2) * C,
            hasX0, xs, Wx0, b0, xp0[(s + 1) & 1], (s + 1) * C,
            hasX1, out, Wx1, b1, xp1[(s - 1) & 1], (s - 1) * C,
            out, C);
    }
}